// Round 1
// baseline (188.662 us; speedup 1.0000x reference)
//
#include <hip/hip_runtime.h>
#include <hip/hip_bf16.h>

typedef __attribute__((ext_vector_type(8))) __bf16 bf16x8;
typedef __attribute__((ext_vector_type(4))) float f32x4;
typedef __attribute__((ext_vector_type(8))) float f32x8;
typedef __attribute__((ext_vector_type(4))) unsigned int u32x4;

static __device__ __forceinline__ unsigned short bf16r(float f) {
  unsigned u = __builtin_bit_cast(unsigned, f);
  return (unsigned short)((u + 0x7FFFu + ((u >> 16) & 1u)) >> 16);
}

// tanh(x) = 1 - 2/(exp2(x*2*log2e)+1); saturates correctly for |x| large.
static __device__ __forceinline__ float ftanh(float x) {
  float e = __builtin_amdgcn_exp2f(x * 2.8853900817779268f);
  return 1.0f - 2.0f * __builtin_amdgcn_rcpf(e + 1.0f);
}

// global->LDS direct copy, 16B per lane (dest = wave-uniform base + lane*16)
static __device__ __forceinline__ void gload_lds16(const void* g, void* l) {
  __builtin_amdgcn_global_load_lds(
      (const __attribute__((address_space(1))) unsigned int*)g,
      (__attribute__((address_space(3))) unsigned int*)l, 16, 0, 0);
}

// ---------------- prologue: pack weights (bf16, frag order) + params --------
// ws layout (bytes):
//   w1pk: [0, 131072)          8 mtiles x 16 ksteps x 64 lanes x 8 bf16 (pi-permuted k)
//   w2pk: [131072, 163840)     8 mtiles x 4 ksteps x 64 lanes x 8 bf16 (pi-permuted k)
//   w3pk: [163840, 196608)     same as w2pk
//   ppk : [196608, 200192)     7 params x [q=4][32] f32, [p][q][t*4+reg] = p[t*16+q*4+reg]
//
// R12: w1 k-order switched from identity to the same pi-permutation as w2/w3:
//   slot (q,j) of kstep s <-> col = s*32 + (j>>2)*16 + q*4 + (j&3)
// This lets each obs load instruction cover a CONTIGUOUS 64B sector per
// 4-lane q-group (lane q reads q*16+{0,64}B of each 128B span) instead of
// half-sectors at 32B stride. With nt (no-allocate) loads the old layout
// fetched every obs line from HBM twice.
__global__ void pack_kernel(const float* __restrict__ w1, const float* __restrict__ w2,
                            const float* __restrict__ w3, const float* __restrict__ b1,
                            const float* __restrict__ g1, const float* __restrict__ be1,
                            const float* __restrict__ b2, const float* __restrict__ g2,
                            const float* __restrict__ be2, const float* __restrict__ b3,
                            unsigned short* __restrict__ w1pk, unsigned short* __restrict__ w2pk,
                            unsigned short* __restrict__ w3pk, float* __restrict__ ppk) {
  int idx = blockIdx.x * 256 + threadIdx.x;
  if (idx < 65536) {            // w1, pi-permuted k-order (R12)
    int j = idx & 7, l = (idx >> 3) & 63, s = (idx >> 9) & 15, t = idx >> 13;
    int row = t * 16 + (l & 15);
    int col = s * 32 + (j >> 2) * 16 + (l >> 4) * 4 + (j & 3);
    w1pk[idx] = bf16r(w1[row * 512 + col]);
  } else if (idx < 81920) {     // w2, pi-permuted k-order
    int i = idx - 65536;
    int j = i & 7, l = (i >> 3) & 63, s = (i >> 9) & 3, t = i >> 11;
    int row = t * 16 + (l & 15);
    int col = (2 * s + (j >> 2)) * 16 + (l >> 4) * 4 + (j & 3);
    w2pk[i] = bf16r(w2[row * 128 + col]);
  } else if (idx < 98304) {     // w3, pi-permuted k-order
    int i = idx - 81920;
    int j = i & 7, l = (i >> 3) & 63, s = (i >> 9) & 3, t = i >> 11;
    int row = t * 16 + (l & 15);
    int col = (2 * s + (j >> 2)) * 16 + (l >> 4) * 4 + (j & 3);
    w3pk[i] = bf16r(w3[row * 128 + col]);
  } else if (idx < 99200) {     // params: b1,g1,be1,b2,g2,be2,b3
    int i = idx - 98304;        // 0..895
    int p = i >> 7;
    int r = i & 127;
    int qq = r >> 5, ii = r & 31;
    int m = (ii >> 2) * 16 + qq * 4 + (ii & 3);
    const float* src = (p == 0) ? b1 : (p == 1) ? g1 : (p == 2) ? be1
                     : (p == 3) ? b2 : (p == 4) ? g2 : (p == 5) ? be2 : b3;
    ppk[i] = src[m];
  }
}

// ---------------- fused backbone: 16 waves/block = 4 waves/SIMD -------------
// R10 post-mortem: burst-width null; amdgpu_waves_per_eu honored (no spill at
// ~160 live). R11: 1024-thr block (16 waves = 4/SIMD, 1 block/CU with 128KB
// LDS) + waves_per_eu(4,4) -> 128-reg budget; R9's slim path (~116 live) fits.
// R12: obs loads re-mapped so each instruction reads 16 rows x contiguous
// 64B (lane q: byte q*16 + {0,64} of each 128B span; k-order permuted in w1pk
// to match). Tests the nt-double-fetch theory (188us ~= 1.72x roofline ~=
// exactly 2x obs-read amplification).
__global__ __launch_bounds__(1024)
__attribute__((amdgpu_waves_per_eu(4, 4)))
void backbone_main(const float* __restrict__ obs,
                   const unsigned char* __restrict__ w1pk_g,
                   const bf16x8* __restrict__ w2pk,
                   const bf16x8* __restrict__ w3pk,
                   const float* __restrict__ ppk,
                   float* __restrict__ out) {
  __shared__ __align__(16) unsigned char w1s[131072];

  const int tid  = threadIdx.x;
  const int lane = tid & 63;
  const int wv   = tid >> 6;          // 0..15
  const int q    = lane >> 4;
  const int rl   = lane & 15;
  // block owns 256 consecutive rows; wave owns 16 of them.
  const size_t brow = (size_t)blockIdx.x * 256 + (unsigned)(wv * 16) + (unsigned)rl;

  // R12: lane q owns floats [q*4, q*4+4) and [16+q*4, 16+q*4+4) of each
  // 32-float kstep -> the 4 q-lanes tile each 64B sector contiguously.
  const float* p0 = obs + brow * 512 + q * 4;

  f32x4 st[2][4];
#define LOAD_BATCH(buf, s0)                                                      \
  do {                                                                           \
    st[buf][0] = __builtin_nontemporal_load((const f32x4*)(p0 + (s0) * 32));     \
    st[buf][1] = __builtin_nontemporal_load((const f32x4*)(p0 + (s0) * 32 + 16));\
    st[buf][2] = __builtin_nontemporal_load((const f32x4*)(p0 + (s0) * 32 + 32));\
    st[buf][3] = __builtin_nontemporal_load((const f32x4*)(p0 + (s0) * 32 + 48));\
  } while (0)

  // preload batches 0,1 (hide under LDS fill latency)
  LOAD_BATCH(0, 0);
  LOAD_BATCH(1, 2);

  // fill w1 into LDS: 8 rounds x (1024 threads x 16B) = 128KB
#pragma unroll
  for (int r = 0; r < 8; ++r) {
    gload_lds16(w1pk_g + r * 16384 + tid * 16, w1s + r * 16384 + wv * 1024);
  }
  __syncthreads();   // the only barrier in the kernel

  const bf16x8* w1l = (const bf16x8*)w1s;   // frag (t,s): [(t*16+s)*64 + lane]

  f32x4 acc[8];
#pragma unroll
  for (int t = 0; t < 8; ++t) acc[t] = (f32x4){0.f, 0.f, 0.f, 0.f};

  // ---- GEMM1: K=512, 8 batches x 2 ksteps, 2 batches in flight ----
#pragma unroll
  for (int bb = 0; bb < 8; ++bb) {
    const int cur = bb & 1;
    f32x4 a0 = st[cur][0], a1 = st[cur][1];
    f32x4 a2 = st[cur][2], a3 = st[cur][3];
    if (bb < 6) {
      LOAD_BATCH(cur, 2 * bb + 4);
    }
    f32x8 r0 = {a0.x, a0.y, a0.z, a0.w, a1.x, a1.y, a1.z, a1.w};
    f32x8 r1 = {a2.x, a2.y, a2.z, a2.w, a3.x, a3.y, a3.z, a3.w};
    bf16x8 b0 = __builtin_convertvector(r0, bf16x8);
    bf16x8 b1 = __builtin_convertvector(r1, bf16x8);
#pragma unroll
    for (int t = 0; t < 8; ++t) {
      bf16x8 af0 = w1l[(t * 16 + 2 * bb) * 64 + lane];
      acc[t] = __builtin_amdgcn_mfma_f32_16x16x32_bf16(af0, b0, acc[t], 0, 0, 0);
    }
#pragma unroll
    for (int t = 0; t < 8; ++t) {
      bf16x8 af1 = w1l[(t * 16 + 2 * bb + 1) * 64 + lane];
      acc[t] = __builtin_amdgcn_mfma_f32_16x16x32_bf16(af1, b1, acc[t], 0, 0, 0);
    }
  }
#undef LOAD_BATCH

  bf16x8 pkv[4];

  // ---- epilogue 1: +b1, LayerNorm(g1,be1), tanh, pack bf16 ----
  {
    const float* pb = ppk + 0 * 128 + q * 32;
    const float* pg = ppk + 1 * 128 + q * 32;
    const float* pe = ppk + 2 * 128 + q * 32;
    float s1 = 0.f, s2 = 0.f;
#pragma unroll
    for (int t = 0; t < 8; ++t) {
      f32x4 bb = *(const f32x4*)(pb + t * 4);
      f32x4 v = acc[t];
      v.x += bb.x; v.y += bb.y; v.z += bb.z; v.w += bb.w;
      acc[t] = v;
      s1 += (v.x + v.y) + (v.z + v.w);
      s2 += (v.x * v.x + v.y * v.y) + (v.z * v.z + v.w * v.w);
    }
    s1 += __shfl_xor(s1, 16, 64);
    s1 += __shfl_xor(s1, 32, 64);
    s2 += __shfl_xor(s2, 16, 64);
    s2 += __shfl_xor(s2, 32, 64);
    float mu  = s1 * (1.0f / 128.0f);
    float var = s2 * (1.0f / 128.0f) - mu * mu;
    float rs  = __builtin_amdgcn_rsqf(var + 1e-5f);
#pragma unroll
    for (int t2 = 0; t2 < 4; ++t2) {
      f32x4 ga = *(const f32x4*)(pg + (2 * t2) * 4);
      f32x4 gb = *(const f32x4*)(pg + (2 * t2 + 1) * 4);
      f32x4 ea = *(const f32x4*)(pe + (2 * t2) * 4);
      f32x4 eb = *(const f32x4*)(pe + (2 * t2 + 1) * 4);
      f32x4 va = acc[2 * t2];
      f32x4 vb = acc[2 * t2 + 1];
      f32x8 cat = {ftanh((va.x - mu) * rs * ga.x + ea.x),
                   ftanh((va.y - mu) * rs * ga.y + ea.y),
                   ftanh((va.z - mu) * rs * ga.z + ea.z),
                   ftanh((va.w - mu) * rs * ga.w + ea.w),
                   ftanh((vb.x - mu) * rs * gb.x + eb.x),
                   ftanh((vb.y - mu) * rs * gb.y + eb.y),
                   ftanh((vb.z - mu) * rs * gb.z + eb.z),
                   ftanh((vb.w - mu) * rs * gb.w + eb.w)};
      pkv[t2] = __builtin_convertvector(cat, bf16x8);
    }
  }

  // ---- GEMM2: K=128 (4 ksteps), B-frags are the lane's own pkv regs ----
#pragma unroll
  for (int t = 0; t < 8; ++t) acc[t] = (f32x4){0.f, 0.f, 0.f, 0.f};
#pragma unroll
  for (int s = 0; s < 4; ++s) {
#pragma unroll
    for (int t = 0; t < 8; ++t) {
      bf16x8 af = w2pk[(t * 4 + s) * 64 + lane];
      acc[t] = __builtin_amdgcn_mfma_f32_16x16x32_bf16(af, pkv[s], acc[t], 0, 0, 0);
    }
  }

  // ---- epilogue 2: +b2, LayerNorm(g2,be2), tanh, pack ----
  {
    const float* pb = ppk + 3 * 128 + q * 32;
    const float* pg = ppk + 4 * 128 + q * 32;
    const float* pe = ppk + 5 * 128 + q * 32;
    float s1 = 0.f, s2 = 0.f;
#pragma unroll
    for (int t = 0; t < 8; ++t) {
      f32x4 bb = *(const f32x4*)(pb + t * 4);
      f32x4 v = acc[t];
      v.x += bb.x; v.y += bb.y; v.z += bb.z; v.w += bb.w;
      acc[t] = v;
      s1 += (v.x + v.y) + (v.z + v.w);
      s2 += (v.x * v.x + v.y * v.y) + (v.z * v.z + v.w * v.w);
    }
    s1 += __shfl_xor(s1, 16, 64);
    s1 += __shfl_xor(s1, 32, 64);
    s2 += __shfl_xor(s2, 16, 64);
    s2 += __shfl_xor(s2, 32, 64);
    float mu  = s1 * (1.0f / 128.0f);
    float var = s2 * (1.0f / 128.0f) - mu * mu;
    float rs  = __builtin_amdgcn_rsqf(var + 1e-5f);
#pragma unroll
    for (int t2 = 0; t2 < 4; ++t2) {
      f32x4 ga = *(const f32x4*)(pg + (2 * t2) * 4);
      f32x4 gb = *(const f32x4*)(pg + (2 * t2 + 1) * 4);
      f32x4 ea = *(const f32x4*)(pe + (2 * t2) * 4);
      f32x4 eb = *(const f32x4*)(pe + (2 * t2 + 1) * 4);
      f32x4 va = acc[2 * t2];
      f32x4 vb = acc[2 * t2 + 1];
      f32x8 cat = {ftanh((va.x - mu) * rs * ga.x + ea.x),
                   ftanh((va.y - mu) * rs * ga.y + ea.y),
                   ftanh((va.z - mu) * rs * ga.z + ea.z),
                   ftanh((va.w - mu) * rs * ga.w + ea.w),
                   ftanh((vb.x - mu) * rs * gb.x + eb.x),
                   ftanh((vb.y - mu) * rs * gb.y + eb.y),
                   ftanh((vb.z - mu) * rs * gb.z + eb.z),
                   ftanh((vb.w - mu) * rs * gb.w + eb.w)};
      pkv[t2] = __builtin_convertvector(cat, bf16x8);
    }
  }

  // ---- GEMM3 ----
#pragma unroll
  for (int t = 0; t < 8; ++t) acc[t] = (f32x4){0.f, 0.f, 0.f, 0.f};
#pragma unroll
  for (int s = 0; s < 4; ++s) {
#pragma unroll
    for (int t = 0; t < 8; ++t) {
      bf16x8 af = w3pk[(t * 4 + s) * 64 + lane];
      acc[t] = __builtin_amdgcn_mfma_f32_16x16x32_bf16(af, pkv[s], acc[t], 0, 0, 0);
    }
  }

  // ---- final: +b3, tanh, store fp32 (dwordx4, nontemporal) ----
  {
    const float* pb = ppk + 6 * 128 + q * 32;
    float* orow = out + brow * 128 + q * 4;
#pragma unroll
    for (int t = 0; t < 8; ++t) {
      f32x4 bb = *(const f32x4*)(pb + t * 4);
      f32x4 v = acc[t];
      f32x4 o = {ftanh(v.x + bb.x), ftanh(v.y + bb.y),
                 ftanh(v.z + bb.z), ftanh(v.w + bb.w)};
      __builtin_nontemporal_store(o, (f32x4*)(orow + t * 16));
    }
  }
}

extern "C" void kernel_launch(void* const* d_in, const int* in_sizes, int n_in,
                              void* d_out, int out_size, void* d_ws, size_t ws_size,
                              hipStream_t stream) {
  const float* obs = (const float*)d_in[0];
  const float* w1  = (const float*)d_in[1];
  const float* b1  = (const float*)d_in[2];
  const float* g1  = (const float*)d_in[3];
  const float* be1 = (const float*)d_in[4];
  const float* w2  = (const float*)d_in[5];
  const float* b2  = (const float*)d_in[6];
  const float* g2  = (const float*)d_in[7];
  const float* be2 = (const float*)d_in[8];
  const float* w3  = (const float*)d_in[9];
  const float* b3  = (const float*)d_in[10];

  unsigned short* w1pk = (unsigned short*)d_ws;
  unsigned short* w2pk = w1pk + 65536;
  unsigned short* w3pk = w2pk + 16384;
  float*          ppk  = (float*)(w3pk + 16384);

  pack_kernel<<<388, 256, 0, stream>>>(w1, w2, w3, b1, g1, be1, b2, g2, be2, b3,
                                       w1pk, w2pk, w3pk, ppk);

  // non-persistent: 1024 blocks x 1024 thr; each block = 256 rows
  backbone_main<<<1024, 1024, 0, stream>>>(obs, (const unsigned char*)w1pk,
                                           (const bf16x8*)w2pk, (const bf16x8*)w3pk,
                                           ppk, (float*)d_out);
}